// Round 6
// baseline (174.513 us; speedup 1.0000x reference)
//
#include <hip/hip_runtime.h>
#include <math.h>
#include <limits.h>

#define NB1 8192      // sample histogram bins: float bits >> 19 (sign+exp+4 mantissa)
#define NB2 4096      // fine linear histogram bins over the band
#define VEC 4         // float4 per array per thread per tile (16 elements)
#define TILE_F4 1024  // float4 per tile (256 threads * VEC)
#define GRID_MAIN 768 // 3 blocks/CU; bench shape: exactly 3 tiles per block

// Persistent device state. Invariant: all-zero at kernel_launch entry.
// Zero-initialized at module load; sample_band's last block restores zeros,
// so every call — including rocprof replays — starts from a clean state.
// (Fine-hist state now lives in d_ws and is fully overwritten each call.)
__device__ unsigned g_H1[NB1];
__device__ float    g_band[2];
__device__ unsigned g_done1 = 0;

// loss = max(x,0) - x*t + log1p(exp(-|x|)) >= 0 ; p = sigmoid(x)
__device__ __forceinline__ void elem_f(float x, float t, float& l, float& p) {
    float e = __expf(-fabsf(x));
    l = fmaxf(x, 0.f) - x * t + __logf(1.f + e);
    float r = __builtin_amdgcn_rcpf(1.f + e);
    p = (x >= 0.f) ? r : e * r;
}

// ---------- k0: 1/32 contiguous-chunk sample -> coarse bit-histogram ----------
// 256 consecutive float4 (4 KB) out of every 8192 (128 KB); 1 float4/thread
// (288 blocks for the bench shape — good CU spread).
// Fused: the LAST block also performs band selection and self-cleans g_H1.
__global__ __launch_bounds__(256) void sample_band_kernel(
    const float4* __restrict__ x4, const float4* __restrict__ t4,
    int n4, long long ks, long long M)
{
    __shared__ unsigned lh[NB1];   // 32 KB
    __shared__ int is_last;
    for (int i = threadIdx.x; i < NB1; i += 256) lh[i] = 0u;
    __syncthreads();

    int tid = blockIdx.x * 256 + threadIdx.x;
    int S4 = n4 >> 5;              // sampled float4 count (1/32)

    // sample index -> float4 index: group (i>>8) of 8192, offset (i&255)
    int f4 = ((tid >> 8) << 13) + (tid & 255);
    bool v = (tid < S4) && (f4 < n4);

    if (v) {
        float4 xa = x4[f4], ta = t4[f4];
        float xs[4] = {xa.x, xa.y, xa.z, xa.w};
        float ts[4] = {ta.x, ta.y, ta.z, ta.w};
        #pragma unroll
        for (int c = 0; c < 4; ++c) {
            float l, p; elem_f(xs[c], ts[c], l, p);
            atomicAdd(&lh[__float_as_uint(l) >> 19], 1u);
        }
    }
    __syncthreads();
    for (int i = threadIdx.x; i < NB1; i += 256) {
        unsigned c = lh[i];
        if (c) atomicAdd(&g_H1[i], c);
    }
    __syncthreads();               // this block's H1 atomics are issued

    if (threadIdx.x == 0) {
        __threadfence();           // release
        is_last = (atomicAdd(&g_done1, 1u) == (unsigned)(gridDim.x - 1));
    }
    __syncthreads();
    if (!is_last) return;
    __threadfence();               // acquire: see all blocks' H1 atomics

    // ---- band selection: pick value band [vlo, vhi) containing kth value ----
    const uint4* hv = (const uint4*)g_H1;
    uint4* lv = (uint4*)lh;
    for (int i = threadIdx.x; i < NB1 / 4; i += 256) lv[i] = hv[i];
    __syncthreads();
    // self-clean persistent state for next call (H1 now staged in LDS)
    for (int i = threadIdx.x; i < NB1; i += 256) g_H1[i] = 0u;
    if (threadIdx.x == 0) g_done1 = 0u;

    if (threadIdx.x < 64) {
        int lane = threadIdx.x;
        int base = lane << 7;          // 128 bins per lane
        unsigned long long chunk = 0;
        for (int j = 0; j < 128; ++j) chunk += lh[base + j];
        unsigned long long s = chunk;  // inclusive suffix-scan across lanes
        #pragma unroll
        for (int off = 1; off < 64; off <<= 1) {
            unsigned long long v2 = __shfl_down(s, off);
            if (lane + off < 64) s += v2;
        }
        unsigned long long above = s - chunk;

        int my_bhi = INT_MAX, my_blo = -1;
        unsigned long long c = above;
        for (int j = 127; j >= 0; --j) {
            unsigned h = lh[base + j];
            if ((long long)(c + h) < ks - M) my_bhi = base + j;
            if ((long long)c > ks + M && my_blo < 0) my_blo = base + j;
            c += h;
        }
        #pragma unroll
        for (int off = 32; off; off >>= 1) {
            int a = __shfl_down(my_bhi, off); my_bhi = min(my_bhi, a);
            int b = __shfl_down(my_blo, off); my_blo = max(my_blo, b);
        }
        if (lane == 0) {
            int bhi = (my_bhi == INT_MAX) ? (NB1 - 1) : my_bhi;
            int blo = my_blo;
            float vhi = __uint_as_float((unsigned)bhi << 19);
            float vlo = (blo < 0) ? 0.f : __uint_as_float((unsigned)(blo + 1) << 19);
            if (!(vlo < vhi)) vlo = 0.f;
            g_band[0] = vlo;
            g_band[1] = vhi;
        }
    }
}

// ---------- k1: full pass; ZERO global atomics; register ping-pong prefetch ----
// 768 fixed blocks, grid-stride over 1024-float4 tiles (bench: exactly 3/block).
// In-band elements bin into a private LDS hist (lgkm domain — vmcnt queue stays
// pure loads); at block end the WHOLE hist is plain-stored (uint4) to this
// block's slot in d_ws. No atomics anywhere -> no L2 line serialization, no
// in-order vmcnt retirement behind atomics.
__global__ __launch_bounds__(256, 4) void main_kernel(
    const float4* __restrict__ x4, const float4* __restrict__ t4,
    unsigned* __restrict__ hcopies,
    float* __restrict__ q0, float* __restrict__ q1,
    float* __restrict__ q2, float* __restrict__ q3, unsigned* __restrict__ qc,
    const float* __restrict__ xg, const float* __restrict__ tg,
    int n, int n4)
{
    __shared__ unsigned lhist[NB2];    // 16 KB private fine-hist
    for (int i = threadIdx.x; i < NB2; i += 256) lhist[i] = 0u;
    __syncthreads();

    float vlo = g_band[0], vhi = g_band[1];
    float scale = (float)NB2 / (vhi - vlo);

    int tid = threadIdx.x;
    int ntiles = (n4 + TILE_F4 - 1) / TILE_F4;
    int fullTiles = n4 / TILE_F4;

    float sp = 0.f, spt = 0.f, st = 0.f, sgt = 0.f;
    unsigned cnt = 0;

    float4 xA[VEC], tA[VEC], xB[VEC], tB[VEC];

#define LOADT(XD, TD, tile) do { \
        int _b = (tile) * TILE_F4 + tid; \
        _Pragma("unroll") \
        for (int _j = 0; _j < VEC; ++_j) XD[_j] = x4[_b + _j * 256]; \
        _Pragma("unroll") \
        for (int _j = 0; _j < VEC; ++_j) TD[_j] = t4[_b + _j * 256]; \
    } while (0)

#define PROCT(XD, TD) do { \
        _Pragma("unroll") \
        for (int _j = 0; _j < VEC; ++_j) { \
            float _xs[4] = {XD[_j].x, XD[_j].y, XD[_j].z, XD[_j].w}; \
            float _ts[4] = {TD[_j].x, TD[_j].y, TD[_j].z, TD[_j].w}; \
            _Pragma("unroll") \
            for (int _c = 0; _c < 4; ++_c) { \
                float _l, _p; \
                elem_f(_xs[_c], _ts[_c], _l, _p); \
                sp += _p; spt += _p * _ts[_c]; st += _ts[_c]; \
                if (_l >= vhi) { cnt++; sgt += _l; } \
                else if (_l >= vlo) { \
                    int _bn = min((int)((_l - vlo) * scale), NB2 - 1); \
                    atomicAdd(&lhist[_bn], 1u); \
                } \
            } \
        } \
    } while (0)

    // full tiles: ping-pong register double-buffer, stride GRID_MAIN
    int t0 = blockIdx.x;
    if (t0 < fullTiles) {
        LOADT(xA, tA, t0);
        int tn = t0 + GRID_MAIN;
        while (tn < fullTiles) {
            LOADT(xB, tB, tn);         // prefetch B while A computes
            PROCT(xA, tA);
            tn += GRID_MAIN;
            if (tn < fullTiles) {
                LOADT(xA, tA, tn);     // prefetch A while B computes
                PROCT(xB, tB);
                tn += GRID_MAIN;
            } else {
                PROCT(xB, tB);
                goto full_done;
            }
        }
        PROCT(xA, tA);
full_done: ;
    }

    // ragged tile (n4 % TILE_F4), owned by its stride-assigned block
    if (fullTiles < ntiles && blockIdx.x == (fullTiles % GRID_MAIN)) {
        int base = fullTiles * TILE_F4 + tid;
        for (int j = 0; j < VEC; ++j) {
            int idx = base + j * 256;
            if (idx < n4) {
                float4 xv = x4[idx], tv = t4[idx];
                float xs[4] = {xv.x, xv.y, xv.z, xv.w};
                float ts[4] = {tv.x, tv.y, tv.z, tv.w};
                #pragma unroll
                for (int c = 0; c < 4; ++c) {
                    float l, p;
                    elem_f(xs[c], ts[c], l, p);
                    sp += p; spt += p * ts[c]; st += ts[c];
                    if (l >= vhi) { cnt++; sgt += l; }
                    else if (l >= vlo) {
                        int b = min((int)((l - vlo) * scale), NB2 - 1);
                        atomicAdd(&lhist[b], 1u);
                    }
                }
            }
        }
    }

    // scalar tail (n % 4) on block 0
    int tail0 = n4 << 2;
    if (blockIdx.x == 0 && tid < (n - tail0)) {
        float x = xg[tail0 + tid], t = tg[tail0 + tid];
        float l, p;
        elem_f(x, t, l, p);
        sp += p; spt += p * t; st += t;
        if (l >= vhi) { cnt++; sgt += l; }
        else if (l >= vlo) {
            int b = min((int)((l - vlo) * scale), NB2 - 1);
            atomicAdd(&lhist[b], 1u);
        }
    }

    // flush: plain uint4 store of the ENTIRE private hist (zeros included) to
    // this block's slot — fully overwrites poison, no atomics, no cleaning.
    __syncthreads();
    {
        uint4* dst = (uint4*)(hcopies + (size_t)blockIdx.x * NB2);
        const uint4* src = (const uint4*)lhist;
        for (int i = tid; i < NB2 / 4; i += 256) dst[i] = src[i];
    }

    // wave -> block reduce, then ONE private slot write per block
    #pragma unroll
    for (int off = 32; off; off >>= 1) {
        sp  += __shfl_down(sp,  off);
        spt += __shfl_down(spt, off);
        st  += __shfl_down(st,  off);
        sgt += __shfl_down(sgt, off);
        cnt += __shfl_down(cnt, off);
    }
    __shared__ float    rs[4][4];
    __shared__ unsigned rc[4];
    int w = tid >> 6;
    if ((tid & 63) == 0) {
        rs[w][0] = sp; rs[w][1] = spt; rs[w][2] = st; rs[w][3] = sgt; rc[w] = cnt;
    }
    __syncthreads();
    if (tid == 0) {
        float a0 = 0, a1 = 0, a2 = 0, a3 = 0;
        unsigned c = 0;
        #pragma unroll
        for (int i = 0; i < 4; ++i) {
            a0 += rs[i][0]; a1 += rs[i][1]; a2 += rs[i][2]; a3 += rs[i][3]; c += rc[i];
        }
        q0[blockIdx.x] = a0; q1[blockIdx.x] = a1; q2[blockIdx.x] = a2;
        q3[blockIdx.x] = a3; qc[blockIdx.x] = c;
    }
#undef LOADT
#undef PROCT
}

// ---------- k2: grid-parallel merge of per-block hist copies ----------
__global__ __launch_bounds__(128) void merge_kernel(
    const unsigned* __restrict__ hcopies, unsigned* __restrict__ merged,
    int ncopies)
{
    int bin = blockIdx.x * 128 + threadIdx.x;   // 32 blocks * 128 = NB2
    unsigned s = 0;
    const unsigned* p = hcopies + bin;
    #pragma unroll 8
    for (int r = 0; r < ncopies; ++r) s += p[(size_t)r * NB2];
    merged[bin] = s;
}

// ---------- k3: reduce partials + resolve threshold bin + emit ----------
__global__ __launch_bounds__(1024) void final_kernel(
    const unsigned* __restrict__ merged,
    const float* __restrict__ q0, const float* __restrict__ q1,
    const float* __restrict__ q2, const float* __restrict__ q3,
    const unsigned* __restrict__ qc, int nblocks,
    float* __restrict__ out, long long k)
{
    __shared__ unsigned lh[NB2];        // 16 KB
    __shared__ double red[16][5];
    __shared__ double fin[5];

    for (int i = threadIdx.x; i < NB2; i += 1024) lh[i] = merged[i];

    double a0 = 0, a1 = 0, a2 = 0, a3 = 0, a4 = 0;
    for (int i = threadIdx.x; i < nblocks; i += 1024) {
        a0 += (double)q0[i]; a1 += (double)q1[i]; a2 += (double)q2[i];
        a3 += (double)q3[i]; a4 += (double)qc[i];
    }
    #pragma unroll
    for (int off = 32; off; off >>= 1) {
        a0 += __shfl_down(a0, off); a1 += __shfl_down(a1, off);
        a2 += __shfl_down(a2, off); a3 += __shfl_down(a3, off);
        a4 += __shfl_down(a4, off);
    }
    int w = threadIdx.x >> 6;
    if ((threadIdx.x & 63) == 0) {
        red[w][0] = a0; red[w][1] = a1; red[w][2] = a2; red[w][3] = a3; red[w][4] = a4;
    }
    __syncthreads();
    if (threadIdx.x == 0) {
        double f0 = 0, f1 = 0, f2 = 0, f3 = 0, f4 = 0;
        for (int i = 0; i < 16; ++i) {
            f0 += red[i][0]; f1 += red[i][1]; f2 += red[i][2];
            f3 += red[i][3]; f4 += red[i][4];
        }
        fin[0] = f0; fin[1] = f1; fin[2] = f2; fin[3] = f3; fin[4] = f4;
    }
    __syncthreads();
    if (threadIdx.x >= 64) return;

    int lane = threadIdx.x;
    double SP = fin[0], SPT = fin[1], ST = fin[2], SGT = fin[3];
    long long CNT = (long long)fin[4];

    double vlo = (double)g_band[0], vhi = (double)g_band[1];
    double binw = (vhi - vlo) / NB2;
    long long k2 = k - CNT;

    int base = lane << 6;               // 64 bins per lane (LDS-resident)
    unsigned long long cchunk = 0;
    double wchunk = 0.0;
    for (int j = 0; j < 64; ++j) {
        unsigned h = lh[base + j];
        cchunk += h;
        wchunk += (double)h * (vlo + (base + j + 0.5) * binw);
    }
    unsigned long long cs = cchunk;
    double wsum = wchunk;
    #pragma unroll
    for (int off = 1; off < 64; off <<= 1) {
        unsigned long long cv = __shfl_down(cs, off);
        double wv = __shfl_down(wsum, off);
        if (lane + off < 64) { cs += cv; wsum += wv; }
    }
    unsigned long long total = __shfl(cs, 0);
    double wtotal = __shfl(wsum, 0);

    double I = SPT, U = SP + ST;
    double dice_part = 0.5 * (1.0 - (2.0 * I + 1e-6) / (U + 1e-6));

    if (k2 <= 0) {
        if (lane == 0) out[0] = (float)(SGT / (double)k + dice_part);
        return;
    }
    if ((unsigned long long)k2 > total) {
        if (lane == 0) {
            double sum_top = SGT + wtotal + (double)(k2 - (long long)total) * vlo;
            out[0] = (float)(sum_top / (double)k + dice_part);
        }
        return;
    }
    unsigned long long c = cs - cchunk;
    double wacc = wsum - wchunk;
    for (int j = 63; j >= 0; --j) {
        unsigned h = lh[base + j];
        double val = vlo + (base + j + 0.5) * binw;
        if (c < (unsigned long long)k2 && (unsigned long long)k2 <= c + h) {
            double sum_top = SGT + wacc + (double)((long long)k2 - (long long)c) * val;
            out[0] = (float)(sum_top / (double)k + dice_part);
        }
        c += h;
        wacc += (double)h * val;
    }
}

extern "C" void kernel_launch(void* const* d_in, const int* in_sizes, int n_in,
                              void* d_out, int out_size, void* d_ws, size_t ws_size,
                              hipStream_t stream)
{
    const float* x = (const float*)d_in[0];
    const float* t = (const float*)d_in[1];
    float* out = (float*)d_out;
    int n = in_sizes[0];
    int n4 = n >> 2;
    long long k = (long long)((double)n * 0.2);   // Python int() truncation
    if (k < 1) k = 1;

    long long S = (long long)(n4 >> 5) * 4;       // sampled element count (1/32)
    long long ks = (S > 0) ? (long long)((double)k * (double)S / (double)n) : 0;
    long long M = 2048;                           // ~9 sigma sample-rank margin

    int S4 = n4 >> 5;                             // sampled float4 count
    int sgrid = (S4 + 255) / 256;                 // 1 float4 per thread
    if (sgrid < 1) sgrid = 1;

    // workspace layout (all regions fully overwritten each call — poison-safe):
    //   [0, 768*16KB)          per-block hist copies
    //   [+0, +16KB)            merged hist
    //   then per-block partials
    unsigned char* ws = (unsigned char*)d_ws;
    unsigned* hcopies = (unsigned*)ws;
    size_t ho = (size_t)GRID_MAIN * NB2 * sizeof(unsigned);        // 12582912
    unsigned* merged = (unsigned*)(ws + ho);
    size_t po = ho + NB2 * sizeof(unsigned);
    size_t pstride = (((size_t)GRID_MAIN * 4) + 255) & ~(size_t)255;
    float*    q0 = (float*)(ws + po);
    float*    q1 = (float*)(ws + po + pstride);
    float*    q2 = (float*)(ws + po + 2 * pstride);
    float*    q3 = (float*)(ws + po + 3 * pstride);
    unsigned* qc = (unsigned*)(ws + po + 4 * pstride);

    sample_band_kernel<<<sgrid, 256, 0, stream>>>((const float4*)x, (const float4*)t,
                                                  n4, ks, M);
    main_kernel<<<GRID_MAIN, 256, 0, stream>>>((const float4*)x, (const float4*)t,
                                               hcopies, q0, q1, q2, q3, qc,
                                               x, t, n, n4);
    merge_kernel<<<NB2 / 128, 128, 0, stream>>>(hcopies, merged, GRID_MAIN);
    final_kernel<<<1, 1024, 0, stream>>>(merged, q0, q1, q2, q3, qc,
                                         GRID_MAIN, out, k);
}

// Round 7
// 148.440 us; speedup vs baseline: 1.1756x; 1.1756x over previous
//
#include <hip/hip_runtime.h>
#include <math.h>
#include <limits.h>

#define NB1 8192      // sample histogram bins: float bits >> 19 (sign+exp+4 mantissa)
#define NB2 4096      // fine linear histogram bins over the band
#define NREP 4        // replicated global fine-hist copies (blockIdx & 3)
#define GRID_MAIN 512 // 2 blocks/CU at 80 KB LDS

// Persistent device state. Invariant: all-zero at kernel_launch entry.
// Zero-initialized at module load; each launch restores zeros before finishing
// (sample_band's last block cleans g_H1/g_done1; final_kernel cleans g_hist2),
// so every call — including rocprof replays — starts from a clean state.
__device__ unsigned g_H1[NB1];
__device__ unsigned g_hist2[NREP * NB2];   // 64 KB, 4 replicated copies
__device__ float    g_band[2];
__device__ unsigned g_done1 = 0;

// loss = max(x,0) - x*t + log1p(exp(-|x|)) >= 0 ; p = sigmoid(x)
__device__ __forceinline__ void elem_f(float x, float t, float& l, float& p) {
    float e = __expf(-fabsf(x));
    l = fmaxf(x, 0.f) - x * t + __logf(1.f + e);
    float r = __builtin_amdgcn_rcpf(1.f + e);
    p = (x >= 0.f) ? r : e * r;
}

// async global -> LDS, 16 B per lane (lands at lds_base + lane*16)
typedef __attribute__((address_space(3))) unsigned       lds_u32;
typedef __attribute__((address_space(1))) const unsigned glb_u32;
__device__ __forceinline__ void gload16(const void* g, void* l) {
    __builtin_amdgcn_global_load_lds((glb_u32*)g, (lds_u32*)l, 16, 0, 0);
}

// ---------- k0: 1/16 chunked sample -> coarse bit-histogram ----------
// (R4-proven config.) Fused: LAST block performs band selection, cleans g_H1.
__global__ __launch_bounds__(256) void sample_band_kernel(
    const float4* __restrict__ x4, const float4* __restrict__ t4,
    int n4, long long ks, long long M)
{
    __shared__ unsigned lh[NB1];   // 32 KB
    __shared__ int is_last;
    for (int i = threadIdx.x; i < NB1; i += 256) lh[i] = 0u;
    __syncthreads();

    int nth = gridDim.x * 256;
    int tid = blockIdx.x * 256 + threadIdx.x;
    int S4 = n4 >> 4;              // sampled float4 pairs
    int i0 = tid, i1 = tid + nth;

    float4 xa, ta, xb, tb;
    bool v0 = i0 < S4, v1 = i1 < S4;
    if (v0) {
        int f4 = ((i0 >> 6) << 10) + (i0 & 63);
        xa = x4[f4]; ta = t4[f4];
    }
    if (v1) {
        int f4 = ((i1 >> 6) << 10) + (i1 & 63);
        xb = x4[f4]; tb = t4[f4];
    }
    if (v0) {
        float xs[4] = {xa.x, xa.y, xa.z, xa.w};
        float ts[4] = {ta.x, ta.y, ta.z, ta.w};
        #pragma unroll
        for (int c = 0; c < 4; ++c) {
            float l, p; elem_f(xs[c], ts[c], l, p);
            atomicAdd(&lh[__float_as_uint(l) >> 19], 1u);
        }
    }
    if (v1) {
        float xs[4] = {xb.x, xb.y, xb.z, xb.w};
        float ts[4] = {tb.x, tb.y, tb.z, tb.w};
        #pragma unroll
        for (int c = 0; c < 4; ++c) {
            float l, p; elem_f(xs[c], ts[c], l, p);
            atomicAdd(&lh[__float_as_uint(l) >> 19], 1u);
        }
    }
    __syncthreads();
    for (int i = threadIdx.x; i < NB1; i += 256) {
        unsigned c = lh[i];
        if (c) atomicAdd(&g_H1[i], c);
    }
    __syncthreads();

    if (threadIdx.x == 0) {
        __threadfence();           // release
        is_last = (atomicAdd(&g_done1, 1u) == (unsigned)(gridDim.x - 1));
    }
    __syncthreads();
    if (!is_last) return;
    __threadfence();               // acquire

    const uint4* hv = (const uint4*)g_H1;
    uint4* lv = (uint4*)lh;
    for (int i = threadIdx.x; i < NB1 / 4; i += 256) lv[i] = hv[i];
    __syncthreads();
    for (int i = threadIdx.x; i < NB1; i += 256) g_H1[i] = 0u;
    if (threadIdx.x == 0) g_done1 = 0u;

    if (threadIdx.x < 64) {
        int lane = threadIdx.x;
        int base = lane << 7;          // 128 bins per lane
        unsigned long long chunk = 0;
        for (int j = 0; j < 128; ++j) chunk += lh[base + j];
        unsigned long long s = chunk;  // inclusive suffix-scan across lanes
        #pragma unroll
        for (int off = 1; off < 64; off <<= 1) {
            unsigned long long v = __shfl_down(s, off);
            if (lane + off < 64) s += v;
        }
        unsigned long long above = s - chunk;

        int my_bhi = INT_MAX, my_blo = -1;
        unsigned long long c = above;
        for (int j = 127; j >= 0; --j) {
            unsigned h = lh[base + j];
            if ((long long)(c + h) < ks - M) my_bhi = base + j;
            if ((long long)c > ks + M && my_blo < 0) my_blo = base + j;
            c += h;
        }
        #pragma unroll
        for (int off = 32; off; off >>= 1) {
            int a = __shfl_down(my_bhi, off); my_bhi = min(my_bhi, a);
            int b = __shfl_down(my_blo, off); my_blo = max(my_blo, b);
        }
        if (lane == 0) {
            int bhi = (my_bhi == INT_MAX) ? (NB1 - 1) : my_bhi;
            int blo = my_blo;
            float vhi = __uint_as_float((unsigned)bhi << 19);
            float vlo = (blo < 0) ? 0.f : __uint_as_float((unsigned)(blo + 1) << 19);
            if (!(vlo < vhi)) vlo = 0.f;
            g_band[0] = vlo;
            g_band[1] = vhi;
        }
    }
}

// ---------- k1: full pass via wave-private global_load_lds pipeline ----------
// Each wave owns a private double-buffered LDS staging region (2 x 4 KB per
// array); chunk = 256 float4 per array per wave. Pipeline per wave:
//   STAGE(c+1) [8 x global_load_lds, no VGPRs] ; s_waitcnt vmcnt(8)  [c ready,
//   c+1 still in flight] ; COMPUTE(c) from LDS.
// No __syncthreads() in the loop -> the compiler's vmcnt(0)-before-barrier
// drain (the m97 stall) never happens. Source-level register prefetch failed
// 3x (compiler sinks loads, VGPR=36 measured); this makes the pipeline
// explicit and un-sinkable.
__global__ __launch_bounds__(256, 2) void main_kernel(
    const float4* __restrict__ x4, const float4* __restrict__ t4,
    float* __restrict__ q0, float* __restrict__ q1,
    float* __restrict__ q2, float* __restrict__ q3, unsigned* __restrict__ qc,
    const float* __restrict__ xg, const float* __restrict__ tg,
    int n, int n4)
{
    __shared__ float4 sx[4][2][256];   // 32 KB: per-wave x staging
    __shared__ float4 sy[4][2][256];   // 32 KB: per-wave t staging
    __shared__ unsigned lhist[NB2];    // 16 KB private fine-hist
    for (int i = threadIdx.x; i < NB2; i += 256) lhist[i] = 0u;
    __syncthreads();

    float vlo = g_band[0], vhi = g_band[1];
    float scale = (float)NB2 / (vhi - vlo);

    int tid = threadIdx.x;
    int lane = tid & 63;
    int w = __builtin_amdgcn_readfirstlane(tid >> 6);   // wave id in block

    int nwaves = gridDim.x * 4;
    int wid = blockIdx.x * 4 + (tid >> 6);
    int fullChunks = n4 >> 8;          // chunks of 256 float4

    float sp = 0.f, spt = 0.f, st = 0.f, sgt = 0.f;
    unsigned cnt = 0;

#define STAGE(c) do { \
        int _p = (c) & 1; \
        const float4* _gx = x4 + ((long long)(c) << 8) + lane; \
        const float4* _gt = t4 + ((long long)(c) << 8) + lane; \
        _Pragma("unroll") \
        for (int _i = 0; _i < 4; ++_i) { \
            gload16(_gx + _i * 64, &sx[w][_p][_i * 64]); \
            gload16(_gt + _i * 64, &sy[w][_p][_i * 64]); \
        } \
    } while (0)

#define COMPUTE(c) do { \
        int _p = (c) & 1; \
        _Pragma("unroll") \
        for (int _j = 0; _j < 4; ++_j) { \
            float4 _xv = sx[w][_p][lane + _j * 64]; \
            float4 _tv = sy[w][_p][lane + _j * 64]; \
            float _xs[4] = {_xv.x, _xv.y, _xv.z, _xv.w}; \
            float _ts[4] = {_tv.x, _tv.y, _tv.z, _tv.w}; \
            _Pragma("unroll") \
            for (int _c = 0; _c < 4; ++_c) { \
                float _l, _pp; \
                elem_f(_xs[_c], _ts[_c], _l, _pp); \
                sp += _pp; spt += _pp * _ts[_c]; st += _ts[_c]; \
                if (_l >= vhi) { cnt++; sgt += _l; } \
                else if (_l >= vlo) { \
                    int _bn = min((int)((_l - vlo) * scale), NB2 - 1); \
                    atomicAdd(&lhist[_bn], 1u); \
                } \
            } \
        } \
    } while (0)

    int c = wid;
    if (c < fullChunks) {
        STAGE(c);
        while (true) {
            int cn = c + nwaves;
            if (cn < fullChunks) {
                STAGE(cn);                                  // 8 newer in flight
                asm volatile("s_waitcnt vmcnt(8)" ::: "memory");  // c is ready
                COMPUTE(c);
                c = cn;
            } else {
                asm volatile("s_waitcnt vmcnt(0)" ::: "memory");
                COMPUTE(c);
                break;
            }
        }
    }

    // ragged chunk (n4 % 256), direct bounds-checked loads by its owner wave
    if ((n4 & 255) != 0 && wid == (fullChunks % nwaves)) {
        int base = (fullChunks << 8) + lane;
        for (int j = 0; j < 4; ++j) {
            int idx = base + j * 64;
            if (idx < n4) {
                float4 xv = x4[idx], tv = t4[idx];
                float xs[4] = {xv.x, xv.y, xv.z, xv.w};
                float ts[4] = {tv.x, tv.y, tv.z, tv.w};
                #pragma unroll
                for (int cc = 0; cc < 4; ++cc) {
                    float l, p;
                    elem_f(xs[cc], ts[cc], l, p);
                    sp += p; spt += p * ts[cc]; st += ts[cc];
                    if (l >= vhi) { cnt++; sgt += l; }
                    else if (l >= vlo) {
                        int b = min((int)((l - vlo) * scale), NB2 - 1);
                        atomicAdd(&lhist[b], 1u);
                    }
                }
            }
        }
    }

    // scalar tail (n % 4) on block 0
    int tail0 = n4 << 2;
    if (blockIdx.x == 0 && tid < (n - tail0)) {
        float x = xg[tail0 + tid], t = tg[tail0 + tid];
        float l, p;
        elem_f(x, t, l, p);
        sp += p; spt += p * t; st += t;
        if (l >= vhi) { cnt++; sgt += l; }
        else if (l >= vlo) {
            int b = min((int)((l - vlo) * scale), NB2 - 1);
            atomicAdd(&lhist[b], 1u);
        }
    }

    // flush private fine-hist: batched full-wave atomics, NREP-way replicated
    __syncthreads();
    {
        unsigned* dst = &g_hist2[(blockIdx.x & (NREP - 1)) * NB2];
        for (int i = tid; i < NB2; i += 256) {
            unsigned cc = lhist[i];
            if (cc) atomicAdd(&dst[i], cc);
        }
    }

    // wave -> block reduce, then ONE private slot write per block
    #pragma unroll
    for (int off = 32; off; off >>= 1) {
        sp  += __shfl_down(sp,  off);
        spt += __shfl_down(spt, off);
        st  += __shfl_down(st,  off);
        sgt += __shfl_down(sgt, off);
        cnt += __shfl_down(cnt, off);
    }
    __shared__ float    rs[4][4];
    __shared__ unsigned rc[4];
    if ((tid & 63) == 0) {
        rs[w][0] = sp; rs[w][1] = spt; rs[w][2] = st; rs[w][3] = sgt; rc[w] = cnt;
    }
    __syncthreads();
    if (tid == 0) {
        float a0 = 0, a1 = 0, a2 = 0, a3 = 0;
        unsigned cc = 0;
        #pragma unroll
        for (int i = 0; i < 4; ++i) {
            a0 += rs[i][0]; a1 += rs[i][1]; a2 += rs[i][2]; a3 += rs[i][3]; cc += rc[i];
        }
        q0[blockIdx.x] = a0; q1[blockIdx.x] = a1; q2[blockIdx.x] = a2;
        q3[blockIdx.x] = a3; qc[blockIdx.x] = cc;
    }
#undef STAGE
#undef COMPUTE
}

// ---------- k2: reduce partials + resolve threshold bin + emit ----------
// Merges the NREP hist copies; self-cleans all of g_hist2 (staged to LDS first).
__global__ __launch_bounds__(1024) void final_kernel(
    const float* __restrict__ q0, const float* __restrict__ q1,
    const float* __restrict__ q2, const float* __restrict__ q3,
    const unsigned* __restrict__ qc, int nblocks,
    float* __restrict__ out, long long k)
{
    __shared__ unsigned lh[NB2];        // 16 KB
    __shared__ double red[16][5];
    __shared__ double fin[5];

    for (int i = threadIdx.x; i < NB2; i += 1024) {
        unsigned s = 0;
        #pragma unroll
        for (int r = 0; r < NREP; ++r) {
            s += g_hist2[r * NB2 + i];
            g_hist2[r * NB2 + i] = 0u;  // self-clean for next call
        }
        lh[i] = s;
    }

    double a0 = 0, a1 = 0, a2 = 0, a3 = 0, a4 = 0;
    for (int i = threadIdx.x; i < nblocks; i += 1024) {
        a0 += (double)q0[i]; a1 += (double)q1[i]; a2 += (double)q2[i];
        a3 += (double)q3[i]; a4 += (double)qc[i];
    }
    #pragma unroll
    for (int off = 32; off; off >>= 1) {
        a0 += __shfl_down(a0, off); a1 += __shfl_down(a1, off);
        a2 += __shfl_down(a2, off); a3 += __shfl_down(a3, off);
        a4 += __shfl_down(a4, off);
    }
    int w = threadIdx.x >> 6;
    if ((threadIdx.x & 63) == 0) {
        red[w][0] = a0; red[w][1] = a1; red[w][2] = a2; red[w][3] = a3; red[w][4] = a4;
    }
    __syncthreads();
    if (threadIdx.x == 0) {
        double f0 = 0, f1 = 0, f2 = 0, f3 = 0, f4 = 0;
        for (int i = 0; i < 16; ++i) {
            f0 += red[i][0]; f1 += red[i][1]; f2 += red[i][2];
            f3 += red[i][3]; f4 += red[i][4];
        }
        fin[0] = f0; fin[1] = f1; fin[2] = f2; fin[3] = f3; fin[4] = f4;
    }
    __syncthreads();
    if (threadIdx.x >= 64) return;

    int lane = threadIdx.x;
    double SP = fin[0], SPT = fin[1], ST = fin[2], SGT = fin[3];
    long long CNT = (long long)fin[4];

    double vlo = (double)g_band[0], vhi = (double)g_band[1];
    double binw = (vhi - vlo) / NB2;
    long long k2 = k - CNT;

    int base = lane << 6;               // 64 bins per lane (LDS-resident)
    unsigned long long cchunk = 0;
    double wchunk = 0.0;
    for (int j = 0; j < 64; ++j) {
        unsigned h = lh[base + j];
        cchunk += h;
        wchunk += (double)h * (vlo + (base + j + 0.5) * binw);
    }
    unsigned long long cs = cchunk;
    double wsum = wchunk;
    #pragma unroll
    for (int off = 1; off < 64; off <<= 1) {
        unsigned long long cv = __shfl_down(cs, off);
        double wv = __shfl_down(wsum, off);
        if (lane + off < 64) { cs += cv; wsum += wv; }
    }
    unsigned long long total = __shfl(cs, 0);
    double wtotal = __shfl(wsum, 0);

    double I = SPT, U = SP + ST;
    double dice_part = 0.5 * (1.0 - (2.0 * I + 1e-6) / (U + 1e-6));

    if (k2 <= 0) {
        if (lane == 0) out[0] = (float)(SGT / (double)k + dice_part);
        return;
    }
    if ((unsigned long long)k2 > total) {
        if (lane == 0) {
            double sum_top = SGT + wtotal + (double)(k2 - (long long)total) * vlo;
            out[0] = (float)(sum_top / (double)k + dice_part);
        }
        return;
    }
    unsigned long long c = cs - cchunk;
    double wacc = wsum - wchunk;
    for (int j = 63; j >= 0; --j) {
        unsigned h = lh[base + j];
        double val = vlo + (base + j + 0.5) * binw;
        if (c < (unsigned long long)k2 && (unsigned long long)k2 <= c + h) {
            double sum_top = SGT + wacc + (double)((long long)k2 - (long long)c) * val;
            out[0] = (float)(sum_top / (double)k + dice_part);
        }
        c += h;
        wacc += (double)h * val;
    }
}

extern "C" void kernel_launch(void* const* d_in, const int* in_sizes, int n_in,
                              void* d_out, int out_size, void* d_ws, size_t ws_size,
                              hipStream_t stream)
{
    const float* x = (const float*)d_in[0];
    const float* t = (const float*)d_in[1];
    float* out = (float*)d_out;
    int n = in_sizes[0];
    int n4 = n >> 2;
    long long k = (long long)((double)n * 0.2);   // Python int() truncation
    if (k < 1) k = 1;

    long long S = (long long)(n4 >> 4) * 4;       // sampled element count (1/16)
    long long ks = (S > 0) ? (long long)((double)k * (double)S / (double)n) : 0;
    long long M = 4096;                           // ~13 sigma sample-rank margin

    int S4 = n4 >> 4;                             // sampled float4 pairs
    int sgrid = (S4 + 511) / 512;                 // 2 pairs per thread
    if (sgrid < 1) sgrid = 1;

    // workspace holds ONLY per-block partials (fully overwritten each call)
    unsigned char* ws = (unsigned char*)d_ws;
    size_t pstride = (((size_t)GRID_MAIN * 4) + 255) & ~(size_t)255;
    float*    q0 = (float*)(ws);
    float*    q1 = (float*)(ws + pstride);
    float*    q2 = (float*)(ws + 2 * pstride);
    float*    q3 = (float*)(ws + 3 * pstride);
    unsigned* qc = (unsigned*)(ws + 4 * pstride);

    sample_band_kernel<<<sgrid, 256, 0, stream>>>((const float4*)x, (const float4*)t,
                                                  n4, ks, M);
    main_kernel<<<GRID_MAIN, 256, 0, stream>>>((const float4*)x, (const float4*)t,
                                               q0, q1, q2, q3, qc, x, t, n, n4);
    final_kernel<<<1, 1024, 0, stream>>>(q0, q1, q2, q3, qc, GRID_MAIN, out, k);
}

// Round 8
// 131.905 us; speedup vs baseline: 1.3230x; 1.1254x over previous
//
#include <hip/hip_runtime.h>
#include <math.h>
#include <limits.h>

#define NB1 2048      // coarse bins: (float_bits >> 17) - OFF1  (64 steps/octave)
#define OFF1 6656     // = 104 << 6 : bin 0 at 2^-23; covers up to 2^9
#define NB2 4096      // fine linear histogram bins over the band
#define NREP 4        // replicated global fine-hist copies (blockIdx & 3)
#define GRID_MAIN 2048 // exactly 8 blocks/CU resident: one generation, no tail

// Persistent device state. Invariant: all-zero at kernel_launch entry.
// Zero-initialized at module load; each launch restores zeros before finishing
// (sample_band's last block cleans g_H1/g_done1; final_kernel cleans g_hist2),
// so every call — including rocprof replays — starts from a clean state.
__device__ unsigned g_H1[NB1];
__device__ unsigned g_hist2[NREP * NB2];   // 64 KB, 4 replicated copies
__device__ float    g_band[2];
__device__ unsigned g_done1 = 0;

// loss = max(x,0) - x*t + log1p(exp(-|x|)) >= 0 ; p = sigmoid(x)
__device__ __forceinline__ void elem_f(float x, float t, float& l, float& p) {
    float e = __expf(-fabsf(x));
    l = fmaxf(x, 0.f) - x * t + __logf(1.f + e);
    float r = __builtin_amdgcn_rcpf(1.f + e);
    p = (x >= 0.f) ? r : e * r;
}

// coarse bin for a non-negative loss value (monotonic in value)
__device__ __forceinline__ int coarse_bin(float l) {
    int b = (int)(__float_as_uint(l) >> 17) - OFF1;
    return min(max(b, 0), NB1 - 1);
}

// ---------- k0: 1/16 chunked sample -> coarse bit-histogram ----------
// (R4-proven sampling layout.) 2048 range-limited coarse bins (64/octave):
// 4x cheaper flush/scan than 8192, and a 4x narrower band for main.
// Fused: LAST block performs band selection, self-cleans g_H1.
__global__ __launch_bounds__(256) void sample_band_kernel(
    const float4* __restrict__ x4, const float4* __restrict__ t4,
    int n4, long long ks, long long M)
{
    __shared__ unsigned lh[NB1];   // 8 KB
    __shared__ int is_last;
    for (int i = threadIdx.x; i < NB1; i += 256) lh[i] = 0u;
    __syncthreads();

    int nth = gridDim.x * 256;
    int tid = blockIdx.x * 256 + threadIdx.x;
    int S4 = n4 >> 4;              // sampled float4 pairs
    int i0 = tid, i1 = tid + nth;

    float4 xa, ta, xb, tb;
    bool v0 = i0 < S4, v1 = i1 < S4;
    if (v0) {
        int f4 = ((i0 >> 6) << 10) + (i0 & 63);
        xa = x4[f4]; ta = t4[f4];
    }
    if (v1) {
        int f4 = ((i1 >> 6) << 10) + (i1 & 63);
        xb = x4[f4]; tb = t4[f4];
    }
    if (v0) {
        float xs[4] = {xa.x, xa.y, xa.z, xa.w};
        float ts[4] = {ta.x, ta.y, ta.z, ta.w};
        #pragma unroll
        for (int c = 0; c < 4; ++c) {
            float l, p; elem_f(xs[c], ts[c], l, p);
            atomicAdd(&lh[coarse_bin(l)], 1u);
        }
    }
    if (v1) {
        float xs[4] = {xb.x, xb.y, xb.z, xb.w};
        float ts[4] = {tb.x, tb.y, tb.z, tb.w};
        #pragma unroll
        for (int c = 0; c < 4; ++c) {
            float l, p; elem_f(xs[c], ts[c], l, p);
            atomicAdd(&lh[coarse_bin(l)], 1u);
        }
    }
    __syncthreads();
    for (int i = threadIdx.x; i < NB1; i += 256) {
        unsigned c = lh[i];
        if (c) atomicAdd(&g_H1[i], c);
    }
    __syncthreads();

    if (threadIdx.x == 0) {
        __threadfence();           // release
        is_last = (atomicAdd(&g_done1, 1u) == (unsigned)(gridDim.x - 1));
    }
    __syncthreads();
    if (!is_last) return;
    __threadfence();               // acquire

    const uint4* hv = (const uint4*)g_H1;
    uint4* lv = (uint4*)lh;
    for (int i = threadIdx.x; i < NB1 / 4; i += 256) lv[i] = hv[i];
    __syncthreads();
    for (int i = threadIdx.x; i < NB1; i += 256) g_H1[i] = 0u;
    if (threadIdx.x == 0) g_done1 = 0u;

    if (threadIdx.x < 64) {
        int lane = threadIdx.x;
        int base = lane << 5;          // 32 bins per lane
        unsigned long long chunk = 0;
        for (int j = 0; j < 32; ++j) chunk += lh[base + j];
        unsigned long long s = chunk;  // inclusive suffix-scan across lanes
        #pragma unroll
        for (int off = 1; off < 64; off <<= 1) {
            unsigned long long v = __shfl_down(s, off);
            if (lane + off < 64) s += v;
        }
        unsigned long long above = s - chunk;

        int my_bhi = INT_MAX, my_blo = -1;
        unsigned long long c = above;
        for (int j = 31; j >= 0; --j) {
            unsigned h = lh[base + j];
            if ((long long)(c + h) < ks - M) my_bhi = base + j;
            if ((long long)c > ks + M && my_blo < 0) my_blo = base + j;
            c += h;
        }
        #pragma unroll
        for (int off = 32; off; off >>= 1) {
            int a = __shfl_down(my_bhi, off); my_bhi = min(my_bhi, a);
            int b = __shfl_down(my_blo, off); my_blo = max(my_blo, b);
        }
        if (lane == 0) {
            int bhi = (my_bhi == INT_MAX) ? (NB1 - 1) : my_bhi;
            int blo = my_blo;
            float vhi = __uint_as_float((unsigned)(bhi + OFF1) << 17);
            float vlo = (blo < 0) ? 0.f
                                  : __uint_as_float((unsigned)(blo + 1 + OFF1) << 17);
            if (!(vlo < vhi)) vlo = 0.f;
            g_band[0] = vlo;
            g_band[1] = vhi;
        }
    }
}

// ---------- k1: single full pass; per-block partials to private slots ----------
// Grid = 2048 = exactly 8 resident blocks/CU (16.5 KB LDS, low VGPR): ONE
// block generation, no straggler tail (the 2304-grid ran 2048 + 256 leftovers
// at 1 block/CU — latency-exposed; R1 measured 42% occupancy on this body).
// Each block owns a contiguous range of n4/2048 float4 (bench: exactly 1152).
// LDS fine-hist in-loop (DS pipe), NREP-replicated atomic flush at block end
// (R4-proven). Narrow band (64-step/octave coarse bins) keeps the masked hist
// path to ~1-2% of lanes.
__global__ __launch_bounds__(256) void main_kernel(
    const float4* __restrict__ x4, const float4* __restrict__ t4,
    float* __restrict__ q0, float* __restrict__ q1,
    float* __restrict__ q2, float* __restrict__ q3, unsigned* __restrict__ qc,
    const float* __restrict__ xg, const float* __restrict__ tg,
    int n, int n4)
{
    __shared__ unsigned lhist[NB2];    // 16 KB private fine-hist
    for (int i = threadIdx.x; i < NB2; i += 256) lhist[i] = 0u;
    __syncthreads();

    float vlo = g_band[0], vhi = g_band[1];
    float scale = (float)NB2 / (vhi - vlo);

    int per = (n4 + GRID_MAIN - 1) / GRID_MAIN;     // float4 per block
    int base = blockIdx.x * per;
    int end = min(base + per, n4);

    float sp = 0.f, spt = 0.f, st = 0.f, sgt = 0.f;
    unsigned cnt = 0;

    for (int idx = base + threadIdx.x; idx < end; idx += 256) {
        float4 xv = x4[idx], tv = t4[idx];
        float xs[4] = {xv.x, xv.y, xv.z, xv.w};
        float ts[4] = {tv.x, tv.y, tv.z, tv.w};
        #pragma unroll
        for (int c = 0; c < 4; ++c) {
            float l, p;
            elem_f(xs[c], ts[c], l, p);
            sp += p; spt += p * ts[c]; st += ts[c];
            if (l >= vhi) { cnt++; sgt += l; }
            else if (l >= vlo) {
                int b = min((int)((l - vlo) * scale), NB2 - 1);
                atomicAdd(&lhist[b], 1u);
            }
        }
    }

    // scalar tail (n % 4) on block 0
    int tail0 = n4 << 2;
    if (blockIdx.x == 0 && threadIdx.x < (n - tail0)) {
        float x = xg[tail0 + threadIdx.x], t = tg[tail0 + threadIdx.x];
        float l, p;
        elem_f(x, t, l, p);
        sp += p; spt += p * t; st += t;
        if (l >= vhi) { cnt++; sgt += l; }
        else if (l >= vlo) {
            int b = min((int)((l - vlo) * scale), NB2 - 1);
            atomicAdd(&lhist[b], 1u);
        }
    }

    // flush private fine-hist: batched full-wave atomics, NREP-way replicated
    __syncthreads();
    {
        unsigned* dst = &g_hist2[(blockIdx.x & (NREP - 1)) * NB2];
        for (int i = threadIdx.x; i < NB2; i += 256) {
            unsigned c = lhist[i];
            if (c) atomicAdd(&dst[i], c);
        }
    }

    // wave -> block reduce, then ONE private slot write per block
    #pragma unroll
    for (int off = 32; off; off >>= 1) {
        sp  += __shfl_down(sp,  off);
        spt += __shfl_down(spt, off);
        st  += __shfl_down(st,  off);
        sgt += __shfl_down(sgt, off);
        cnt += __shfl_down(cnt, off);
    }
    __shared__ float    rs[4][4];
    __shared__ unsigned rc[4];
    int w = threadIdx.x >> 6;
    if ((threadIdx.x & 63) == 0) {
        rs[w][0] = sp; rs[w][1] = spt; rs[w][2] = st; rs[w][3] = sgt; rc[w] = cnt;
    }
    __syncthreads();
    if (threadIdx.x == 0) {
        float a0 = 0, a1 = 0, a2 = 0, a3 = 0;
        unsigned c = 0;
        #pragma unroll
        for (int i = 0; i < 4; ++i) {
            a0 += rs[i][0]; a1 += rs[i][1]; a2 += rs[i][2]; a3 += rs[i][3]; c += rc[i];
        }
        q0[blockIdx.x] = a0; q1[blockIdx.x] = a1; q2[blockIdx.x] = a2;
        q3[blockIdx.x] = a3; qc[blockIdx.x] = c;
    }
}

// ---------- k2: reduce partials + resolve threshold bin + emit ----------
// Merges the NREP hist copies; self-cleans all of g_hist2 (staged to LDS first).
__global__ __launch_bounds__(1024) void final_kernel(
    const float* __restrict__ q0, const float* __restrict__ q1,
    const float* __restrict__ q2, const float* __restrict__ q3,
    const unsigned* __restrict__ qc, int nblocks,
    float* __restrict__ out, long long k)
{
    __shared__ unsigned lh[NB2];        // 16 KB
    __shared__ double red[16][5];
    __shared__ double fin[5];

    for (int i = threadIdx.x; i < NB2; i += 1024) {
        unsigned s = 0;
        #pragma unroll
        for (int r = 0; r < NREP; ++r) {
            s += g_hist2[r * NB2 + i];
            g_hist2[r * NB2 + i] = 0u;  // self-clean for next call
        }
        lh[i] = s;
    }

    double a0 = 0, a1 = 0, a2 = 0, a3 = 0, a4 = 0;
    for (int i = threadIdx.x; i < nblocks; i += 1024) {
        a0 += (double)q0[i]; a1 += (double)q1[i]; a2 += (double)q2[i];
        a3 += (double)q3[i]; a4 += (double)qc[i];
    }
    #pragma unroll
    for (int off = 32; off; off >>= 1) {
        a0 += __shfl_down(a0, off); a1 += __shfl_down(a1, off);
        a2 += __shfl_down(a2, off); a3 += __shfl_down(a3, off);
        a4 += __shfl_down(a4, off);
    }
    int w = threadIdx.x >> 6;
    if ((threadIdx.x & 63) == 0) {
        red[w][0] = a0; red[w][1] = a1; red[w][2] = a2; red[w][3] = a3; red[w][4] = a4;
    }
    __syncthreads();
    if (threadIdx.x == 0) {
        double f0 = 0, f1 = 0, f2 = 0, f3 = 0, f4 = 0;
        for (int i = 0; i < 16; ++i) {
            f0 += red[i][0]; f1 += red[i][1]; f2 += red[i][2];
            f3 += red[i][3]; f4 += red[i][4];
        }
        fin[0] = f0; fin[1] = f1; fin[2] = f2; fin[3] = f3; fin[4] = f4;
    }
    __syncthreads();
    if (threadIdx.x >= 64) return;

    int lane = threadIdx.x;
    double SP = fin[0], SPT = fin[1], ST = fin[2], SGT = fin[3];
    long long CNT = (long long)fin[4];

    double vlo = (double)g_band[0], vhi = (double)g_band[1];
    double binw = (vhi - vlo) / NB2;
    long long k2 = k - CNT;

    int base = lane << 6;               // 64 bins per lane (LDS-resident)
    unsigned long long cchunk = 0;
    double wchunk = 0.0;
    for (int j = 0; j < 64; ++j) {
        unsigned h = lh[base + j];
        cchunk += h;
        wchunk += (double)h * (vlo + (base + j + 0.5) * binw);
    }
    unsigned long long cs = cchunk;
    double wsum = wchunk;
    #pragma unroll
    for (int off = 1; off < 64; off <<= 1) {
        unsigned long long cv = __shfl_down(cs, off);
        double wv = __shfl_down(wsum, off);
        if (lane + off < 64) { cs += cv; wsum += wv; }
    }
    unsigned long long total = __shfl(cs, 0);
    double wtotal = __shfl(wsum, 0);

    double I = SPT, U = SP + ST;
    double dice_part = 0.5 * (1.0 - (2.0 * I + 1e-6) / (U + 1e-6));

    if (k2 <= 0) {
        if (lane == 0) out[0] = (float)(SGT / (double)k + dice_part);
        return;
    }
    if ((unsigned long long)k2 > total) {
        if (lane == 0) {
            double sum_top = SGT + wtotal + (double)(k2 - (long long)total) * vlo;
            out[0] = (float)(sum_top / (double)k + dice_part);
        }
        return;
    }
    unsigned long long c = cs - cchunk;
    double wacc = wsum - wchunk;
    for (int j = 63; j >= 0; --j) {
        unsigned h = lh[base + j];
        double val = vlo + (base + j + 0.5) * binw;
        if (c < (unsigned long long)k2 && (unsigned long long)k2 <= c + h) {
            double sum_top = SGT + wacc + (double)((long long)k2 - (long long)c) * val;
            out[0] = (float)(sum_top / (double)k + dice_part);
        }
        c += h;
        wacc += (double)h * val;
    }
}

extern "C" void kernel_launch(void* const* d_in, const int* in_sizes, int n_in,
                              void* d_out, int out_size, void* d_ws, size_t ws_size,
                              hipStream_t stream)
{
    const float* x = (const float*)d_in[0];
    const float* t = (const float*)d_in[1];
    float* out = (float*)d_out;
    int n = in_sizes[0];
    int n4 = n >> 2;
    long long k = (long long)((double)n * 0.2);   // Python int() truncation
    if (k < 1) k = 1;

    long long S = (long long)(n4 >> 4) * 4;       // sampled element count (1/16)
    long long ks = (S > 0) ? (long long)((double)k * (double)S / (double)n) : 0;
    long long M = 4096;                           // ~6.7 sigma sample-rank margin

    int S4 = n4 >> 4;                             // sampled float4 pairs
    int sgrid = (S4 + 511) / 512;                 // 2 pairs per thread
    if (sgrid < 1) sgrid = 1;

    // workspace holds ONLY per-block partials (fully overwritten each call)
    unsigned char* ws = (unsigned char*)d_ws;
    size_t pstride = (((size_t)GRID_MAIN * 4) + 255) & ~(size_t)255;
    float*    q0 = (float*)(ws);
    float*    q1 = (float*)(ws + pstride);
    float*    q2 = (float*)(ws + 2 * pstride);
    float*    q3 = (float*)(ws + 3 * pstride);
    unsigned* qc = (unsigned*)(ws + 4 * pstride);

    sample_band_kernel<<<sgrid, 256, 0, stream>>>((const float4*)x, (const float4*)t,
                                                  n4, ks, M);
    main_kernel<<<GRID_MAIN, 256, 0, stream>>>((const float4*)x, (const float4*)t,
                                               q0, q1, q2, q3, qc, x, t, n, n4);
    final_kernel<<<1, 1024, 0, stream>>>(q0, q1, q2, q3, qc, GRID_MAIN, out, k);
}